// Round 1
// baseline (274.866 us; speedup 1.0000x reference)
//
#include <hip/hip_runtime.h>
#include <hip/hip_fp16.h>

#define NXK 2048
#define NYK 2048
#define NC  (NXK - 1)   // 2047 cells per dim

// ---------------- build: per-cell packed fp16 Hermite record (32 B) ----------------
// rec[cell] = 16 halfs: [f00,f01,f10,f11, gx00..gx11, gy00..gy11, gxy00..gxy11]
// gx = fx*dx, gy = fy*dy, gxy = fxy*dx*dy (premultiplied; raw fx ~ O(1e4) would
// lose fp16 accuracy, fx*dx ~ O(1) is safe).
// v2: 2 cells per thread, float2 row loads (j even -> 8B aligned), 64B contiguous store.
__global__ __launch_bounds__(256) void build2_kernel(
    const float* __restrict__ xk, const float* __restrict__ yk,
    const float* __restrict__ f,  const float* __restrict__ fx,
    const float* __restrict__ fy, const float* __restrict__ fxy,
    __half* __restrict__ rec)
{
    int p = blockIdx.x * blockDim.x + threadIdx.x;   // cell-pair index
    int j = p * 2;
    int i = blockIdx.y;
    if (j >= NC) return;
    bool has2 = (j + 1) < NC;   // second cell valid (implies col j+3 <= 2047)

    size_t b0 = (size_t)i * NYK + j;   // row i, col j
    size_t b1 = b0 + NYK;              // row i+1

    float dx = xk[i + 1] - xk[i];
    float y0 = yk[j], y1 = yk[j + 1];
    float y2 = has2 ? yk[j + 2] : y1;
    float dyA = y1 - y0;
    float dyB = y2 - y1;
    float dxyA = dx * dyA;
    float dxyB = dx * dyB;

    float2 z = make_float2(0.0f, 0.0f);
    // A = cols (j, j+1), B = cols (j+2, j+3); rows 0 = i, 1 = i+1
    float2 fA0 = *reinterpret_cast<const float2*>(f   + b0);
    float2 fA1 = *reinterpret_cast<const float2*>(f   + b1);
    float2 xA0 = *reinterpret_cast<const float2*>(fx  + b0);
    float2 xA1 = *reinterpret_cast<const float2*>(fx  + b1);
    float2 yA0 = *reinterpret_cast<const float2*>(fy  + b0);
    float2 yA1 = *reinterpret_cast<const float2*>(fy  + b1);
    float2 wA0 = *reinterpret_cast<const float2*>(fxy + b0);
    float2 wA1 = *reinterpret_cast<const float2*>(fxy + b1);
    float2 fB0 = z, fB1 = z, xB0 = z, xB1 = z, yB0 = z, yB1 = z, wB0 = z, wB1 = z;
    if (has2) {
        fB0 = *reinterpret_cast<const float2*>(f   + b0 + 2);
        fB1 = *reinterpret_cast<const float2*>(f   + b1 + 2);
        xB0 = *reinterpret_cast<const float2*>(fx  + b0 + 2);
        xB1 = *reinterpret_cast<const float2*>(fx  + b1 + 2);
        yB0 = *reinterpret_cast<const float2*>(fy  + b0 + 2);
        yB1 = *reinterpret_cast<const float2*>(fy  + b1 + 2);
        wB0 = *reinterpret_cast<const float2*>(fxy + b0 + 2);
        wB1 = *reinterpret_cast<const float2*>(fxy + b1 + 2);
    }

    union { __half h[16]; float4 v[2]; } rA, rB;
    // cell j: corners (i,j) (i,j+1) (i+1,j) (i+1,j+1)
    rA.h[0]  = __float2half(fA0.x);        rA.h[1]  = __float2half(fA0.y);
    rA.h[2]  = __float2half(fA1.x);        rA.h[3]  = __float2half(fA1.y);
    rA.h[4]  = __float2half(xA0.x * dx);   rA.h[5]  = __float2half(xA0.y * dx);
    rA.h[6]  = __float2half(xA1.x * dx);   rA.h[7]  = __float2half(xA1.y * dx);
    rA.h[8]  = __float2half(yA0.x * dyA);  rA.h[9]  = __float2half(yA0.y * dyA);
    rA.h[10] = __float2half(yA1.x * dyA);  rA.h[11] = __float2half(yA1.y * dyA);
    rA.h[12] = __float2half(wA0.x * dxyA); rA.h[13] = __float2half(wA0.y * dxyA);
    rA.h[14] = __float2half(wA1.x * dxyA); rA.h[15] = __float2half(wA1.y * dxyA);
    // cell j+1: corners (i,j+1) (i,j+2) (i+1,j+1) (i+1,j+2)
    rB.h[0]  = __float2half(fA0.y);        rB.h[1]  = __float2half(fB0.x);
    rB.h[2]  = __float2half(fA1.y);        rB.h[3]  = __float2half(fB1.x);
    rB.h[4]  = __float2half(xA0.y * dx);   rB.h[5]  = __float2half(xB0.x * dx);
    rB.h[6]  = __float2half(xA1.y * dx);   rB.h[7]  = __float2half(xB1.x * dx);
    rB.h[8]  = __float2half(yA0.y * dyB);  rB.h[9]  = __float2half(yB0.x * dyB);
    rB.h[10] = __float2half(yA1.y * dyB);  rB.h[11] = __float2half(yB1.x * dyB);
    rB.h[12] = __float2half(wA0.y * dxyB); rB.h[13] = __float2half(wB0.x * dxyB);
    rB.h[14] = __float2half(wA1.y * dxyB); rB.h[15] = __float2half(wB1.x * dxyB);

    float4* outp = reinterpret_cast<float4*>(rec + ((size_t)i * NC + j) * 16);
    outp[0] = rA.v[0];
    outp[1] = rA.v[1];
    if (has2) {
        outp[2] = rB.v[0];
        outp[3] = rB.v[1];
    }
}

// ---------------- gather: 2 queries per thread, records loaded up-front ----------------
__device__ __forceinline__ int locate(float v, const float* __restrict__ k, int n) {
    int i = (int)floorf(v * (float)(n - 1));
    i = min(max(i, 0), n - 2);
    // exact searchsorted(side='right') semantics vs the real (linspace-rounded) knots
    while (i < n - 2 && v >= k[i + 1]) ++i;
    while (i > 0 && v < k[i]) --i;
    return i;
}

struct RecU { union { float4 v[2]; __half2 h2[8]; }; };

__device__ __forceinline__ float eval_cell(float tx, float ty, const RecU& r) {
    // t-powers through interpax's A_CUBIC (note A[3,3] = -1)
    float u0 = 1.0f + tx * tx * (2.0f * tx - 3.0f);
    float u1 = tx * tx * (3.0f - 2.0f * tx);
    float u2 = tx * (1.0f + tx * (tx - 2.0f));
    float u3 = -tx * tx * (1.0f + tx);

    float v0 = 1.0f + ty * ty * (2.0f * ty - 3.0f);
    float v1 = ty * ty * (3.0f - 2.0f * ty);
    float v2 = ty * (1.0f + ty * (ty - 2.0f));
    float v3 = -ty * ty * (1.0f + ty);

    float2 a, b;
    a = __half22float2(r.h2[0]); b = __half22float2(r.h2[1]);
    float sf   = u0 * a.x + u2 * a.y + u1 * b.x + u3 * b.y;
    a = __half22float2(r.h2[2]); b = __half22float2(r.h2[3]);
    float sgx  = u0 * a.x + u2 * a.y + u1 * b.x + u3 * b.y;
    a = __half22float2(r.h2[4]); b = __half22float2(r.h2[5]);
    float sgy  = u0 * a.x + u2 * a.y + u1 * b.x + u3 * b.y;
    a = __half22float2(r.h2[6]); b = __half22float2(r.h2[7]);
    float sgxy = u0 * a.x + u2 * a.y + u1 * b.x + u3 * b.y;

    return v0 * sf + v1 * sgx + v2 * sgy + v3 * sgxy;
}

__global__ __launch_bounds__(256) void gather2_kernel(
    const float* __restrict__ xq, const float* __restrict__ yq,
    const float* __restrict__ xk, const float* __restrict__ yk,
    const __half* __restrict__ rec,
    float* __restrict__ out, int nq, int half)
{
    int t = blockIdx.x * blockDim.x + threadIdx.x;
    if (t >= half) return;
    int q0 = t;
    int q1t = t + half;
    bool has1 = q1t < nq;
    int q1 = has1 ? q1t : q0;

    // streaming data: non-temporal so the record table keeps L2/L3 residency
    float xv0 = __builtin_nontemporal_load(xq + q0);
    float yv0 = __builtin_nontemporal_load(yq + q0);
    float xv1 = __builtin_nontemporal_load(xq + q1);
    float yv1 = __builtin_nontemporal_load(yq + q1);

    int il0 = locate(xv0, xk, NXK);
    int jl0 = locate(yv0, yk, NYK);
    int il1 = locate(xv1, xk, NXK);
    int jl1 = locate(yv1, yk, NYK);

    // issue all 4 random 16B record loads before consuming any (2x MLP/thread)
    const float4* rp0 = reinterpret_cast<const float4*>(rec) + ((size_t)il0 * NC + jl0) * 2;
    const float4* rp1 = reinterpret_cast<const float4*>(rec) + ((size_t)il1 * NC + jl1) * 2;
    RecU r0, r1;
    r0.v[0] = rp0[0];
    r0.v[1] = rp0[1];
    r1.v[0] = rp1[0];
    r1.v[1] = rp1[1];

    float x00 = xk[il0], dx0 = xk[il0 + 1] - x00;
    float tx0 = (xv0 - x00) * ((dx0 == 0.0f) ? 0.0f : 1.0f / dx0);
    float y00 = yk[jl0], dy0 = yk[jl0 + 1] - y00;
    float ty0 = (yv0 - y00) * ((dy0 == 0.0f) ? 0.0f : 1.0f / dy0);

    float x01 = xk[il1], dx1 = xk[il1 + 1] - x01;
    float tx1 = (xv1 - x01) * ((dx1 == 0.0f) ? 0.0f : 1.0f / dx1);
    float y01 = yk[jl1], dy1 = yk[jl1 + 1] - y01;
    float ty1 = (yv1 - y01) * ((dy1 == 0.0f) ? 0.0f : 1.0f / dy1);

    float o0 = eval_cell(tx0, ty0, r0);
    __builtin_nontemporal_store(o0, out + q0);
    if (has1) {
        float o1 = eval_cell(tx1, ty1, r1);
        __builtin_nontemporal_store(o1, out + q1);
    }
}

// ---------------- fallback (round-1 direct gather) ----------------
__global__ __launch_bounds__(256) void interp2d_direct(
    const float* __restrict__ xq, const float* __restrict__ yq,
    const float* __restrict__ xk, const float* __restrict__ yk,
    const float* __restrict__ f,  const float* __restrict__ fx,
    const float* __restrict__ fy, const float* __restrict__ fxy,
    float* __restrict__ out, int nq)
{
    int q = blockIdx.x * blockDim.x + threadIdx.x;
    if (q >= nq) return;

    float xv = xq[q];
    float yv = yq[q];

    int il = locate(xv, xk, NXK);
    int jl = locate(yv, yk, NYK);

    float x0 = xk[il], x1 = xk[il + 1];
    float dx = x1 - x0;
    float tx = (xv - x0) * ((dx == 0.0f) ? 0.0f : 1.0f / dx);
    float y0 = yk[jl], y1 = yk[jl + 1];
    float dy = y1 - y0;
    float ty = (yv - y0) * ((dy == 0.0f) ? 0.0f : 1.0f / dy);

    float u0 = 1.0f + tx * tx * (2.0f * tx - 3.0f);
    float u1 = tx * tx * (3.0f - 2.0f * tx);
    float u2 = tx * (1.0f + tx * (tx - 2.0f));
    float u3 = -tx * tx * (1.0f + tx);
    float v0 = 1.0f + ty * ty * (2.0f * ty - 3.0f);
    float v1 = ty * ty * (3.0f - 2.0f * ty);
    float v2 = ty * (1.0f + ty * (ty - 2.0f));
    float v3 = -ty * ty * (1.0f + ty);

    long base = (long)il * NYK + jl;
    const float* p = f + base;
    float sf   = u0 * p[0] + u2 * p[1] + u1 * p[NYK] + u3 * p[NYK + 1];
    p = fx + base;
    float sfx  = u0 * p[0] + u2 * p[1] + u1 * p[NYK] + u3 * p[NYK + 1];
    p = fy + base;
    float sfy  = u0 * p[0] + u2 * p[1] + u1 * p[NYK] + u3 * p[NYK + 1];
    p = fxy + base;
    float sfxy = u0 * p[0] + u2 * p[1] + u1 * p[NYK] + u3 * p[NYK + 1];

    out[q] = v0 * sf + v1 * (sfx * dx) + v2 * (sfy * dy) + v3 * (sfxy * (dx * dy));
}

extern "C" void kernel_launch(void* const* d_in, const int* in_sizes, int n_in,
                              void* d_out, int out_size, void* d_ws, size_t ws_size,
                              hipStream_t stream) {
    const float* xq  = (const float*)d_in[0];
    const float* yq  = (const float*)d_in[1];
    const float* xk  = (const float*)d_in[2];
    const float* yk  = (const float*)d_in[3];
    const float* f   = (const float*)d_in[4];
    const float* fx  = (const float*)d_in[5];
    const float* fy  = (const float*)d_in[6];
    const float* fxy = (const float*)d_in[7];
    float* out = (float*)d_out;

    int nq = in_sizes[0];
    const size_t rec_bytes = (size_t)NC * NC * 16 * sizeof(__half);  // ~134 MB

    if (ws_size >= rec_bytes) {
        __half* rec = (__half*)d_ws;
        int npairs = (NC + 1) / 2;                       // 1024
        dim3 bgrid((npairs + 255) / 256, NC);            // (4, 2047)
        build2_kernel<<<bgrid, 256, 0, stream>>>(xk, yk, f, fx, fy, fxy, rec);
        int half = (nq + 1) / 2;
        int grid = (half + 255) / 256;
        gather2_kernel<<<grid, 256, 0, stream>>>(xq, yq, xk, yk, rec, out, nq, half);
    } else {
        int grid = (nq + 255) / 256;
        interp2d_direct<<<grid, 256, 0, stream>>>(xq, yq, xk, yk, f, fx, fy, fxy, out, nq);
    }
}

// Round 2
// 253.926 us; speedup vs baseline: 1.0825x; 1.0825x over previous
//
#include <hip/hip_runtime.h>
#include <hip/hip_fp16.h>

#define NXK 2048
#define NYK 2048
#define NC  (NXK - 1)   // 2047 cells per dim

// ---------------- build: per-cell packed fp16 Hermite record (32 B) ----------------
// rec[cell] = 16 halfs: [f00,f01,f10,f11, gx00..gx11, gy00..gy11, gxy00..gxy11]
// gx = fx*dx, gy = fy*dy, gxy = fxy*dx*dy  (premultiplied at build time;
// raw fx ~ O(1e4) would lose fp16 accuracy, fx*dx ~ O(1) is safe).
// NOTE: reverted to the round-0 build verbatim (the 257.5 us configuration) to
// disambiguate the round-1 total-time regression (build2 vs harness noise).
__global__ __launch_bounds__(256) void build_kernel(
    const float* __restrict__ xk, const float* __restrict__ yk,
    const float* __restrict__ f,  const float* __restrict__ fx,
    const float* __restrict__ fy, const float* __restrict__ fxy,
    __half* __restrict__ rec)
{
    int j = blockIdx.x * blockDim.x + threadIdx.x;
    int i = blockIdx.y;
    if (j >= NC) return;

    size_t base = (size_t)i * NYK + j;
    float dx = xk[i + 1] - xk[i];
    float dy = yk[j + 1] - yk[j];
    float dxy = dx * dy;

    union { __half h[16]; float4 v[2]; } r;

    r.h[0]  = __float2half(f[base]);
    r.h[1]  = __float2half(f[base + 1]);
    r.h[2]  = __float2half(f[base + NYK]);
    r.h[3]  = __float2half(f[base + NYK + 1]);

    r.h[4]  = __float2half(fx[base] * dx);
    r.h[5]  = __float2half(fx[base + 1] * dx);
    r.h[6]  = __float2half(fx[base + NYK] * dx);
    r.h[7]  = __float2half(fx[base + NYK + 1] * dx);

    r.h[8]  = __float2half(fy[base] * dy);
    r.h[9]  = __float2half(fy[base + 1] * dy);
    r.h[10] = __float2half(fy[base + NYK] * dy);
    r.h[11] = __float2half(fy[base + NYK + 1] * dy);

    r.h[12] = __float2half(fxy[base] * dxy);
    r.h[13] = __float2half(fxy[base + 1] * dxy);
    r.h[14] = __float2half(fxy[base + NYK] * dxy);
    r.h[15] = __float2half(fxy[base + NYK + 1] * dxy);

    float4* outp = reinterpret_cast<float4*>(rec + ((size_t)i * NC + j) * 16);
    outp[0] = r.v[0];
    outp[1] = r.v[1];
}

// ---------------- gather: 4 queries per thread, records loaded up-front ----------------
// locate(): floorf initial guess + searchsorted-exact correction loops.
// The correction loops are REQUIRED for correctness: interpax's A_CUBIC has
// u3(t) = -t^2(1+t) (== -2 at t=1), so the reference interpolant is
// DISCONTINUOUS at knots; cell selection must match searchsorted bit-exactly.
__device__ __forceinline__ int locate(float v, const float* __restrict__ k, int n) {
    int i = (int)floorf(v * (float)(n - 1));
    i = min(max(i, 0), n - 2);
    while (i < n - 2 && v >= k[i + 1]) ++i;
    while (i > 0 && v < k[i]) --i;
    return i;
}

struct RecU { union { float4 v[2]; __half2 h2[8]; }; };

__device__ __forceinline__ float eval_cell(float tx, float ty, const RecU& r) {
    // t-powers through interpax's A_CUBIC (note A[3,3] = -1)
    float u0 = 1.0f + tx * tx * (2.0f * tx - 3.0f);
    float u1 = tx * tx * (3.0f - 2.0f * tx);
    float u2 = tx * (1.0f + tx * (tx - 2.0f));
    float u3 = -tx * tx * (1.0f + tx);

    float v0 = 1.0f + ty * ty * (2.0f * ty - 3.0f);
    float v1 = ty * ty * (3.0f - 2.0f * ty);
    float v2 = ty * (1.0f + ty * (ty - 2.0f));
    float v3 = -ty * ty * (1.0f + ty);

    float2 a, b;
    a = __half22float2(r.h2[0]); b = __half22float2(r.h2[1]);
    float sf   = u0 * a.x + u2 * a.y + u1 * b.x + u3 * b.y;
    a = __half22float2(r.h2[2]); b = __half22float2(r.h2[3]);
    float sgx  = u0 * a.x + u2 * a.y + u1 * b.x + u3 * b.y;
    a = __half22float2(r.h2[4]); b = __half22float2(r.h2[5]);
    float sgy  = u0 * a.x + u2 * a.y + u1 * b.x + u3 * b.y;
    a = __half22float2(r.h2[6]); b = __half22float2(r.h2[7]);
    float sgxy = u0 * a.x + u2 * a.y + u1 * b.x + u3 * b.y;

    return v0 * sf + v1 * sgx + v2 * sgy + v3 * sgxy;
}

__global__ __launch_bounds__(256) void gather4_kernel(
    const float* __restrict__ xq, const float* __restrict__ yq,
    const float* __restrict__ xk, const float* __restrict__ yk,
    const __half* __restrict__ rec,
    float* __restrict__ out, int nq, int quarter)
{
    int t = blockIdx.x * blockDim.x + threadIdx.x;
    if (t >= quarter) return;

    int   qi[4];
    bool  ok[4];
    float xv[4], yv[4];
#pragma unroll
    for (int k = 0; k < 4; ++k) {
        int q = t + k * quarter;
        ok[k] = (q < nq);
        qi[k] = ok[k] ? q : t;
        // streaming data: non-temporal so the record table keeps L2/L3 residency
        xv[k] = __builtin_nontemporal_load(xq + qi[k]);
        yv[k] = __builtin_nontemporal_load(yq + qi[k]);
    }

    int il[4], jl[4];
#pragma unroll
    for (int k = 0; k < 4; ++k) {
        il[k] = locate(xv[k], xk, NXK);
        jl[k] = locate(yv[k], yk, NYK);
    }

    // issue all 8 random 16B record loads before consuming any (4x MLP/thread)
    RecU r[4];
#pragma unroll
    for (int k = 0; k < 4; ++k) {
        const float4* rp = reinterpret_cast<const float4*>(rec)
                         + ((size_t)il[k] * NC + jl[k]) * 2;
        r[k].v[0] = rp[0];
        r[k].v[1] = rp[1];
    }

#pragma unroll
    for (int k = 0; k < 4; ++k) {
        float x0 = xk[il[k]], dxv = xk[il[k] + 1] - x0;
        float tx = (xv[k] - x0) * ((dxv == 0.0f) ? 0.0f : 1.0f / dxv);
        float y0 = yk[jl[k]], dyv = yk[jl[k] + 1] - y0;
        float ty = (yv[k] - y0) * ((dyv == 0.0f) ? 0.0f : 1.0f / dyv);
        float o = eval_cell(tx, ty, r[k]);
        if (ok[k]) __builtin_nontemporal_store(o, out + qi[k]);
    }
}

// ---------------- fallback (round-1 direct gather) ----------------
__global__ __launch_bounds__(256) void interp2d_direct(
    const float* __restrict__ xq, const float* __restrict__ yq,
    const float* __restrict__ xk, const float* __restrict__ yk,
    const float* __restrict__ f,  const float* __restrict__ fx,
    const float* __restrict__ fy, const float* __restrict__ fxy,
    float* __restrict__ out, int nq)
{
    int q = blockIdx.x * blockDim.x + threadIdx.x;
    if (q >= nq) return;

    float xv = xq[q];
    float yv = yq[q];

    int il = locate(xv, xk, NXK);
    int jl = locate(yv, yk, NYK);

    float x0 = xk[il], x1 = xk[il + 1];
    float dx = x1 - x0;
    float tx = (xv - x0) * ((dx == 0.0f) ? 0.0f : 1.0f / dx);
    float y0 = yk[jl], y1 = yk[jl + 1];
    float dy = y1 - y0;
    float ty = (yv - y0) * ((dy == 0.0f) ? 0.0f : 1.0f / dy);

    float u0 = 1.0f + tx * tx * (2.0f * tx - 3.0f);
    float u1 = tx * tx * (3.0f - 2.0f * tx);
    float u2 = tx * (1.0f + tx * (tx - 2.0f));
    float u3 = -tx * tx * (1.0f + tx);
    float v0 = 1.0f + ty * ty * (2.0f * ty - 3.0f);
    float v1 = ty * ty * (3.0f - 2.0f * ty);
    float v2 = ty * (1.0f + ty * (ty - 2.0f));
    float v3 = -ty * ty * (1.0f + ty);

    long base = (long)il * NYK + jl;
    const float* p = f + base;
    float sf   = u0 * p[0] + u2 * p[1] + u1 * p[NYK] + u3 * p[NYK + 1];
    p = fx + base;
    float sfx  = u0 * p[0] + u2 * p[1] + u1 * p[NYK] + u3 * p[NYK + 1];
    p = fy + base;
    float sfy  = u0 * p[0] + u2 * p[1] + u1 * p[NYK] + u3 * p[NYK + 1];
    p = fxy + base;
    float sfxy = u0 * p[0] + u2 * p[1] + u1 * p[NYK] + u3 * p[NYK + 1];

    out[q] = v0 * sf + v1 * (sfx * dx) + v2 * (sfy * dy) + v3 * (sfxy * (dx * dy));
}

extern "C" void kernel_launch(void* const* d_in, const int* in_sizes, int n_in,
                              void* d_out, int out_size, void* d_ws, size_t ws_size,
                              hipStream_t stream) {
    const float* xq  = (const float*)d_in[0];
    const float* yq  = (const float*)d_in[1];
    const float* xk  = (const float*)d_in[2];
    const float* yk  = (const float*)d_in[3];
    const float* f   = (const float*)d_in[4];
    const float* fx  = (const float*)d_in[5];
    const float* fy  = (const float*)d_in[6];
    const float* fxy = (const float*)d_in[7];
    float* out = (float*)d_out;

    int nq = in_sizes[0];
    const size_t rec_bytes = (size_t)NC * NC * 16 * sizeof(__half);  // ~134 MB

    if (ws_size >= rec_bytes) {
        __half* rec = (__half*)d_ws;
        dim3 bgrid((NC + 255) / 256, NC);
        build_kernel<<<bgrid, 256, 0, stream>>>(xk, yk, f, fx, fy, fxy, rec);
        int quarter = (nq + 3) / 4;
        int grid = (quarter + 255) / 256;
        gather4_kernel<<<grid, 256, 0, stream>>>(xq, yq, xk, yk, rec, out, nq, quarter);
    } else {
        int grid = (nq + 255) / 256;
        interp2d_direct<<<grid, 256, 0, stream>>>(xq, yq, xk, yk, f, fx, fy, fxy, out, nq);
    }
}

// Round 3
// 243.640 us; speedup vs baseline: 1.1282x; 1.0422x over previous
//
#include <hip/hip_runtime.h>
#include <hip/hip_fp16.h>

#define NXK 2048
#define NYK 2048
#define NC  (NXK - 1)   // 2047 cells per dim

#define NTL(p) __builtin_nontemporal_load(p)

// ---------------- build: per-cell packed fp16 Hermite record (32 B) ----------------
// rec[cell] = 16 halfs: [f00,f01,f10,f11, gx00..gx11, gy00..gy11, gxy00..gxy11]
// gx = fx*dx, gy = fy*dy, gxy = fxy*dx*dy  (premultiplied at build time;
// raw fx ~ O(1e4) would lose fp16 accuracy, fx*dx ~ O(1) is safe).
// v3 (vertical pair): each thread emits cells (2i,j) and (2i+1,j), reading node
// rows 2i..2i+2 ONCE (v0 read 4 row-instances per 2 cell-rows; adjacent cell-rows
// land on different XCDs so the overlap row was an L2 miss). Inputs nt-loaded
// (streamed once; keeps L2/L3 lines free for the rec table the gather needs).
// rec stores stay TEMPORAL so the table lands in L2/L3 ahead of the gather.
__global__ __launch_bounds__(256) void build_pair_kernel(
    const float* __restrict__ xk, const float* __restrict__ yk,
    const float* __restrict__ f,  const float* __restrict__ fx,
    const float* __restrict__ fy, const float* __restrict__ fxy,
    __half* __restrict__ rec)
{
    int j  = blockIdx.x * blockDim.x + threadIdx.x;   // cell col
    int i0 = blockIdx.y * 2;                          // first cell row of pair
    if (j >= NC) return;
    bool has2 = (i0 + 1) < NC;                        // second cell row valid

    size_t r0 = (size_t)i0 * NYK + j;
    size_t r1 = r0 + NYK;
    size_t r2 = r1 + NYK;

    float dx0 = xk[i0 + 1] - xk[i0];
    float dx1 = has2 ? (xk[i0 + 2] - xk[i0 + 1]) : 0.0f;
    float dy  = yk[j + 1] - yk[j];

    // node rows i0, i0+1 (always), i0+2 (if has2); cols j, j+1; 4 arrays
    float f00 = NTL(f + r0),  f01 = NTL(f + r0 + 1);
    float f10 = NTL(f + r1),  f11 = NTL(f + r1 + 1);
    float x00 = NTL(fx + r0), x01 = NTL(fx + r0 + 1);
    float x10 = NTL(fx + r1), x11 = NTL(fx + r1 + 1);
    float y00 = NTL(fy + r0), y01 = NTL(fy + r0 + 1);
    float y10 = NTL(fy + r1), y11 = NTL(fy + r1 + 1);
    float w00 = NTL(fxy + r0), w01 = NTL(fxy + r0 + 1);
    float w10 = NTL(fxy + r1), w11 = NTL(fxy + r1 + 1);

    float f20 = 0.f, f21 = 0.f, x20 = 0.f, x21 = 0.f;
    float y20 = 0.f, y21 = 0.f, w20 = 0.f, w21 = 0.f;
    if (has2) {
        f20 = NTL(f + r2);  f21 = NTL(f + r2 + 1);
        x20 = NTL(fx + r2); x21 = NTL(fx + r2 + 1);
        y20 = NTL(fy + r2); y21 = NTL(fy + r2 + 1);
        w20 = NTL(fxy + r2); w21 = NTL(fxy + r2 + 1);
    }

    union { __half h[16]; float4 v[2]; } rA;
    float dxy0 = dx0 * dy;
    rA.h[0]  = __float2half(f00);        rA.h[1]  = __float2half(f01);
    rA.h[2]  = __float2half(f10);        rA.h[3]  = __float2half(f11);
    rA.h[4]  = __float2half(x00 * dx0);  rA.h[5]  = __float2half(x01 * dx0);
    rA.h[6]  = __float2half(x10 * dx0);  rA.h[7]  = __float2half(x11 * dx0);
    rA.h[8]  = __float2half(y00 * dy);   rA.h[9]  = __float2half(y01 * dy);
    rA.h[10] = __float2half(y10 * dy);   rA.h[11] = __float2half(y11 * dy);
    rA.h[12] = __float2half(w00 * dxy0); rA.h[13] = __float2half(w01 * dxy0);
    rA.h[14] = __float2half(w10 * dxy0); rA.h[15] = __float2half(w11 * dxy0);

    float4* outA = reinterpret_cast<float4*>(rec + ((size_t)i0 * NC + j) * 16);
    outA[0] = rA.v[0];
    outA[1] = rA.v[1];

    if (has2) {
        union { __half h[16]; float4 v[2]; } rB;
        float dxy1 = dx1 * dy;
        rB.h[0]  = __float2half(f10);        rB.h[1]  = __float2half(f11);
        rB.h[2]  = __float2half(f20);        rB.h[3]  = __float2half(f21);
        rB.h[4]  = __float2half(x10 * dx1);  rB.h[5]  = __float2half(x11 * dx1);
        rB.h[6]  = __float2half(x20 * dx1);  rB.h[7]  = __float2half(x21 * dx1);
        rB.h[8]  = __float2half(y10 * dy);   rB.h[9]  = __float2half(y11 * dy);
        rB.h[10] = __float2half(y20 * dy);   rB.h[11] = __float2half(y21 * dy);
        rB.h[12] = __float2half(w10 * dxy1); rB.h[13] = __float2half(w11 * dxy1);
        rB.h[14] = __float2half(w20 * dxy1); rB.h[15] = __float2half(w21 * dxy1);

        float4* outB = reinterpret_cast<float4*>(rec + ((size_t)(i0 + 1) * NC + j) * 16);
        outB[0] = rB.v[0];
        outB[1] = rB.v[1];
    }
}

// ---------------- gather: 2 queries per thread (best measured config) ----------------
// locate(): floorf initial guess + searchsorted-exact correction loops.
// The correction loops are REQUIRED for correctness: interpax's A_CUBIC has
// u3(t) = -t^2(1+t) (== -2 at t=1), so the reference interpolant is
// DISCONTINUOUS at knots; cell selection must match searchsorted bit-exactly.
__device__ __forceinline__ int locate(float v, const float* __restrict__ k, int n) {
    int i = (int)floorf(v * (float)(n - 1));
    i = min(max(i, 0), n - 2);
    while (i < n - 2 && v >= k[i + 1]) ++i;
    while (i > 0 && v < k[i]) --i;
    return i;
}

struct RecU { union { float4 v[2]; __half2 h2[8]; }; };

__device__ __forceinline__ float eval_cell(float tx, float ty, const RecU& r) {
    // t-powers through interpax's A_CUBIC (note A[3,3] = -1)
    float u0 = 1.0f + tx * tx * (2.0f * tx - 3.0f);
    float u1 = tx * tx * (3.0f - 2.0f * tx);
    float u2 = tx * (1.0f + tx * (tx - 2.0f));
    float u3 = -tx * tx * (1.0f + tx);

    float v0 = 1.0f + ty * ty * (2.0f * ty - 3.0f);
    float v1 = ty * ty * (3.0f - 2.0f * ty);
    float v2 = ty * (1.0f + ty * (ty - 2.0f));
    float v3 = -ty * ty * (1.0f + ty);

    float2 a, b;
    a = __half22float2(r.h2[0]); b = __half22float2(r.h2[1]);
    float sf   = u0 * a.x + u2 * a.y + u1 * b.x + u3 * b.y;
    a = __half22float2(r.h2[2]); b = __half22float2(r.h2[3]);
    float sgx  = u0 * a.x + u2 * a.y + u1 * b.x + u3 * b.y;
    a = __half22float2(r.h2[4]); b = __half22float2(r.h2[5]);
    float sgy  = u0 * a.x + u2 * a.y + u1 * b.x + u3 * b.y;
    a = __half22float2(r.h2[6]); b = __half22float2(r.h2[7]);
    float sgxy = u0 * a.x + u2 * a.y + u1 * b.x + u3 * b.y;

    return v0 * sf + v1 * sgx + v2 * sgy + v3 * sgxy;
}

__global__ __launch_bounds__(256) void gather2_kernel(
    const float* __restrict__ xq, const float* __restrict__ yq,
    const float* __restrict__ xk, const float* __restrict__ yk,
    const __half* __restrict__ rec,
    float* __restrict__ out, int nq, int half)
{
    int t = blockIdx.x * blockDim.x + threadIdx.x;
    if (t >= half) return;
    int q0 = t;
    int q1t = t + half;
    bool has1 = q1t < nq;
    int q1 = has1 ? q1t : q0;

    // streaming data: non-temporal so the record table keeps L2/L3 residency
    float xv0 = __builtin_nontemporal_load(xq + q0);
    float yv0 = __builtin_nontemporal_load(yq + q0);
    float xv1 = __builtin_nontemporal_load(xq + q1);
    float yv1 = __builtin_nontemporal_load(yq + q1);

    int il0 = locate(xv0, xk, NXK);
    int jl0 = locate(yv0, yk, NYK);
    int il1 = locate(xv1, xk, NXK);
    int jl1 = locate(yv1, yk, NYK);

    // issue all 4 random 16B record loads before consuming any (2x MLP/thread)
    const float4* rp0 = reinterpret_cast<const float4*>(rec) + ((size_t)il0 * NC + jl0) * 2;
    const float4* rp1 = reinterpret_cast<const float4*>(rec) + ((size_t)il1 * NC + jl1) * 2;
    RecU r0, r1;
    r0.v[0] = rp0[0];
    r0.v[1] = rp0[1];
    r1.v[0] = rp1[0];
    r1.v[1] = rp1[1];

    float x00 = xk[il0], dx0 = xk[il0 + 1] - x00;
    float tx0 = (xv0 - x00) * ((dx0 == 0.0f) ? 0.0f : 1.0f / dx0);
    float y00 = yk[jl0], dy0 = yk[jl0 + 1] - y00;
    float ty0 = (yv0 - y00) * ((dy0 == 0.0f) ? 0.0f : 1.0f / dy0);

    float x01 = xk[il1], dx1 = xk[il1 + 1] - x01;
    float tx1 = (xv1 - x01) * ((dx1 == 0.0f) ? 0.0f : 1.0f / dx1);
    float y01 = yk[jl1], dy1 = yk[jl1 + 1] - y01;
    float ty1 = (yv1 - y01) * ((dy1 == 0.0f) ? 0.0f : 1.0f / dy1);

    float o0 = eval_cell(tx0, ty0, r0);
    __builtin_nontemporal_store(o0, out + q0);
    if (has1) {
        float o1 = eval_cell(tx1, ty1, r1);
        __builtin_nontemporal_store(o1, out + q1);
    }
}

// ---------------- fallback (direct gather, no workspace) ----------------
__global__ __launch_bounds__(256) void interp2d_direct(
    const float* __restrict__ xq, const float* __restrict__ yq,
    const float* __restrict__ xk, const float* __restrict__ yk,
    const float* __restrict__ f,  const float* __restrict__ fx,
    const float* __restrict__ fy, const float* __restrict__ fxy,
    float* __restrict__ out, int nq)
{
    int q = blockIdx.x * blockDim.x + threadIdx.x;
    if (q >= nq) return;

    float xv = xq[q];
    float yv = yq[q];

    int il = locate(xv, xk, NXK);
    int jl = locate(yv, yk, NYK);

    float x0 = xk[il], x1 = xk[il + 1];
    float dx = x1 - x0;
    float tx = (xv - x0) * ((dx == 0.0f) ? 0.0f : 1.0f / dx);
    float y0 = yk[jl], y1 = yk[jl + 1];
    float dy = y1 - y0;
    float ty = (yv - y0) * ((dy == 0.0f) ? 0.0f : 1.0f / dy);

    float u0 = 1.0f + tx * tx * (2.0f * tx - 3.0f);
    float u1 = tx * tx * (3.0f - 2.0f * tx);
    float u2 = tx * (1.0f + tx * (tx - 2.0f));
    float u3 = -tx * tx * (1.0f + tx);
    float v0 = 1.0f + ty * ty * (2.0f * ty - 3.0f);
    float v1 = ty * ty * (3.0f - 2.0f * ty);
    float v2 = ty * (1.0f + ty * (ty - 2.0f));
    float v3 = -ty * ty * (1.0f + ty);

    long base = (long)il * NYK + jl;
    const float* p = f + base;
    float sf   = u0 * p[0] + u2 * p[1] + u1 * p[NYK] + u3 * p[NYK + 1];
    p = fx + base;
    float sfx  = u0 * p[0] + u2 * p[1] + u1 * p[NYK] + u3 * p[NYK + 1];
    p = fy + base;
    float sfy  = u0 * p[0] + u2 * p[1] + u1 * p[NYK] + u3 * p[NYK + 1];
    p = fxy + base;
    float sfxy = u0 * p[0] + u2 * p[1] + u1 * p[NYK] + u3 * p[NYK + 1];

    out[q] = v0 * sf + v1 * (sfx * dx) + v2 * (sfy * dy) + v3 * (sfxy * (dx * dy));
}

extern "C" void kernel_launch(void* const* d_in, const int* in_sizes, int n_in,
                              void* d_out, int out_size, void* d_ws, size_t ws_size,
                              hipStream_t stream) {
    const float* xq  = (const float*)d_in[0];
    const float* yq  = (const float*)d_in[1];
    const float* xk  = (const float*)d_in[2];
    const float* yk  = (const float*)d_in[3];
    const float* f   = (const float*)d_in[4];
    const float* fx  = (const float*)d_in[5];
    const float* fy  = (const float*)d_in[6];
    const float* fxy = (const float*)d_in[7];
    float* out = (float*)d_out;

    int nq = in_sizes[0];
    const size_t rec_bytes = (size_t)NC * NC * 16 * sizeof(__half);  // ~134 MB

    if (ws_size >= rec_bytes) {
        __half* rec = (__half*)d_ws;
        int npairs = (NC + 1) / 2;                        // 1024 row pairs
        dim3 bgrid((NC + 255) / 256, npairs);             // (8, 1024)
        build_pair_kernel<<<bgrid, 256, 0, stream>>>(xk, yk, f, fx, fy, fxy, rec);
        int half = (nq + 1) / 2;
        int grid = (half + 255) / 256;
        gather2_kernel<<<grid, 256, 0, stream>>>(xq, yq, xk, yk, rec, out, nq, half);
    } else {
        int grid = (nq + 255) / 256;
        interp2d_direct<<<grid, 256, 0, stream>>>(xq, yq, xk, yk, f, fx, fy, fxy, out, nq);
    }
}